// Round 1
// 871.390 us; speedup vs baseline: 1.0590x; 1.0590x over previous
//
#include <hip/hip_runtime.h>
#include <math.h>

// ---------------- types / helpers ----------------
typedef float f32x4 __attribute__((ext_vector_type(4)));
typedef __bf16 bf16x8 __attribute__((ext_vector_type(8)));
typedef unsigned short u16x8 __attribute__((ext_vector_type(8)));

__device__ __forceinline__ unsigned short f2bf(float f) {
  unsigned u = __float_as_uint(f);
  return (unsigned short)((u + 0x7fffu + ((u >> 16) & 1u)) >> 16);
}
__device__ __forceinline__ float bf2f(unsigned short s) {
  return __uint_as_float(((unsigned)s) << 16);
}
__device__ __forceinline__ void unpk(unsigned v, float& a, float& b) {
  a = __uint_as_float(v << 16);
  b = __uint_as_float(v & 0xffff0000u);
}
__device__ __forceinline__ bf16x8 ld8bf(const unsigned short* p) {
  uint4 u = *(const uint4*)p;
  return __builtin_bit_cast(bf16x8, u);
}
__device__ __forceinline__ bf16x8 pack8(const float* f) {
  u16x8 t;
#pragma unroll
  for (int i = 0; i < 8; ++i) t[i] = f2bf(f[i]);
  return __builtin_bit_cast(bf16x8, t);
}
__device__ __forceinline__ bf16x8 ld8f32(const float* p) {
  float4 a = *(const float4*)p;
  float4 b = *(const float4*)(p + 4);
  float f[8] = {a.x, a.y, a.z, a.w, b.x, b.y, b.z, b.w};
  return pack8(f);
}
__device__ __forceinline__ f32x4 mfma16(bf16x8 a, bf16x8 b, f32x4 c) {
  return __builtin_amdgcn_mfma_f32_16x16x32_bf16(a, b, c, 0, 0, 0);
}

// ---------------- workspace layout (bytes) ----------------
#define TOPO_OFF   0u           // [65536][64] bf16 = 8 MB
#define CENDT_OFF  8388608u     // [64][4160]  bf16 = 532480 (K=4096 quad + 64 Wend tail)
#define FINV_OFF   8921088u     // [64][64] bf16
#define MET_OFF    8929280u     // [64][64] bf16 (metric, symmetric)
#define WU_OFF     8937472u     // [64][64] bf16 (U1 @ o_w)
#define WC_OFF     8945664u     // [64][64] bf16 (S1 @ o_w)
#define WENDF_OFF  8953856u     // [64][64] f32  (Wend, for k_cend)
#define BU_OFF     8970240u     // [64] f32
#define BC_OFF     8970496u     // [64] f32
#define BEND_OFF   8970752u     // [64] f32
#define COSD_OFF   8971008u     // [8][8] f32  cos(dphi)/sqrt(8)
#define TKP_OFF    8971264u     // [64][1024] bf16 tk padded (k = 4j+d, d==3 -> 0)

// =======================================================================
// Launch 0: tk_pad[o][4j+d] = bf16(tk[o][j][d]), d==3 slot = 0.
// K padded 768 -> 1024 so each MFMA A-fragment 8-slice = exactly 2 whole
// j-records -> topo kernel needs no LDS repack and no barriers.
// =======================================================================
__global__ __launch_bounds__(256) void k_pretk(const float* __restrict__ tk,
                                               char* __restrict__ ws) {
  const int e = blockIdx.x * 256 + threadIdx.x;  // 65536 total
  const int o = e >> 10, kk = e & 1023, j = kk >> 2, d = kk & 3;
  const float v = (d < 3) ? tk[((size_t)o * 256 + j) * 3 + d] : 0.f;
  ((unsigned short*)(ws + TKP_OFF))[e] = f2bf(v);
}

// =======================================================================
// Launch 1: topo (blocks 0..1023, 64 rows each) + setup (blocks 1024..1026)
// topo[b,o] = sum_{j,d} (pers[j,b,d,0]+pers[j,b,d,1]) * tk[o,j,d]
// Barrier-free streaming MFMA: each wave owns 16 b-rows; lane (m,quad)
// loads its own 2 j-records (6x float2) per k-step, pair-sums in regs,
// packs the padded 8-wide A-slice; B from bf16 tk_pad (L2-resident).
// 1-deep register prefetch keeps ~3KB/wave of HBM loads in flight.
// =======================================================================
__global__ __launch_bounds__(256, 4) void k_setup_topo(
    const float* __restrict__ pers, const float* __restrict__ tk,
    const float* __restrict__ fisher_m, const float* __restrict__ morphisms,
    const float* __restrict__ functor_w, const float* __restrict__ obj_emb,
    const float* __restrict__ out_w, const float* __restrict__ proj_w,
    const float* __restrict__ proj_b, const float* __restrict__ out_b,
    const float* __restrict__ update_w, const float* __restrict__ update_b,
    const float* __restrict__ state_w, const float* __restrict__ state_b,
    const float* __restrict__ o_w, const float* __restrict__ o_b,
    const float* __restrict__ metric_m, const float* __restrict__ phase,
    char* __restrict__ ws)
{
  __shared__ char smem[33280];
  const int bid = blockIdx.x, tid = threadIdx.x;

  if (bid < 1024) {
    // ---- topo path: barrier-free, LDS-free ----
    const int w = tid >> 6, lane = tid & 63;
    const int m = lane & 15, quad = lane >> 4;
    const size_t rowbase = (size_t)bid * 64 + w * 16;
    const size_t b = rowbase + m;
    const unsigned short* tkp = (const unsigned short*)(ws + TKP_OFF);
    const float* pbase = pers + b * 6;  // + j * 65536*6 per j

    f32x4 acc[4] = {};
    float2 c0, c1, c2, c3, c4, c5;
    {
      const float* p0 = pbase + (size_t)(quad * 2) * 393216;
      c0 = *(const float2*)(p0);
      c1 = *(const float2*)(p0 + 2);
      c2 = *(const float2*)(p0 + 4);
      const float* p1 = p0 + 393216;
      c3 = *(const float2*)(p1);
      c4 = *(const float2*)(p1 + 2);
      c5 = *(const float2*)(p1 + 4);
    }
    for (int ks = 0; ks < 32; ++ks) {
      float f[8] = {c0.x + c0.y, c1.x + c1.y, c2.x + c2.y, 0.f,
                    c3.x + c3.y, c4.x + c4.y, c5.x + c5.y, 0.f};
      bf16x8 a = pack8(f);
      if (ks + 1 < 32) {  // prefetch next k-step's 2 j-records
        const int jn = (ks + 1) * 8 + quad * 2;
        const float* p0 = pbase + (size_t)jn * 393216;
        c0 = *(const float2*)(p0);
        c1 = *(const float2*)(p0 + 2);
        c2 = *(const float2*)(p0 + 4);
        const float* p1 = p0 + 393216;
        c3 = *(const float2*)(p1);
        c4 = *(const float2*)(p1 + 2);
        c5 = *(const float2*)(p1 + 4);
      }
      const unsigned short* bk = tkp + ks * 32 + quad * 8;
#pragma unroll
      for (int nt = 0; nt < 4; ++nt) {
        bf16x8 bb = ld8bf(bk + (size_t)(nt * 16 + m) * 1024);
        acc[nt] = mfma16(a, bb, acc[nt]);
      }
    }
    unsigned short* topo_bf = (unsigned short*)(ws + TOPO_OFF);
#pragma unroll
    for (int nt = 0; nt < 4; ++nt)
#pragma unroll
      for (int r = 0; r < 4; ++r)
        topo_bf[(rowbase + quad * 4 + r) * 64 + nt * 16 + m] = f2bf(acc[nt][r]);

  } else if (bid == 1024) {
    // ---- fisher = F F^T ; Gauss-Jordan inverse (SPD -> no pivoting) ----
    float* aug = (float*)smem;  // [64][130]
    for (int e = tid; e < 4096; e += 256) {
      const int r = e >> 6, c = e & 63;
      float s = 0.f;
      for (int l = 0; l < 64; ++l) s += fisher_m[r * 64 + l] * fisher_m[c * 64 + l];
      aug[r * 130 + c] = s;
      aug[r * 130 + 64 + c] = (r == c) ? 1.f : 0.f;
    }
    __syncthreads();
    const int rr = tid >> 2, cs = tid & 3;
    for (int p = 0; p < 64; ++p) {
      const float piv = 1.f / aug[p * 130 + p];
      const float f = (rr != p) ? aug[rr * 130 + p] : 0.f;
      __syncthreads();
      if (tid < 130) aug[p * 130 + tid] *= piv;
      __syncthreads();
      if (rr != p)
        for (int c = cs; c < 130; c += 4)
          aug[rr * 130 + c] -= f * aug[p * 130 + c];
      __syncthreads();
    }
    unsigned short* finv = (unsigned short*)(ws + FINV_OFF);
    for (int e = tid; e < 4096; e += 256)
      finv[e] = f2bf(aug[(e >> 6) * 130 + 64 + (e & 63)]);

  } else if (bid == 1025) {
    // ---- m_eff -> T2 -> T3 -> Wend, bend ----
    float* L0 = (float*)smem;
    float* L1s = (float*)(smem + 16384);
    float* fw = (float*)(smem + 32768);
    if (tid < 64) {
      float mx = functor_w[0];
      for (int i2 = 1; i2 < 64; ++i2) mx = fmaxf(mx, functor_w[i2]);
      float se = 0.f;
      for (int i2 = 0; i2 < 64; ++i2) se += expf(functor_w[i2] - mx);
      fw[tid] = expf(functor_w[tid] - mx) / se;
    }
    __syncthreads();
    for (int e = tid; e < 4096; e += 256) {  // m_eff[p][q]
      const int p = e >> 6, q = e & 63;
      float s = 0.f;
      for (int m2 = 0; m2 < 64; ++m2) s += fw[m2] * morphisms[m2 * 4096 + p * 64 + q];
      L0[e] = s;
    }
    __syncthreads();
    for (int e = tid; e < 4096; e += 256) {  // T2[m][q] = obj_emb @ m_eff
      const int mm2 = e >> 6, q = e & 63;
      float s = 0.f;
      for (int p = 0; p < 64; ++p) s += obj_emb[mm2 * 64 + p] * L0[p * 64 + q];
      L1s[e] = s;
    }
    __syncthreads();
    for (int e = tid; e < 4096; e += 256) {  // T3[m][n] = T2 @ out_w^T
      const int mm2 = e >> 6, n = e & 63;
      float s = 0.f;
      for (int q = 0; q < 64; ++q) s += L1s[mm2 * 64 + q] * out_w[n * 64 + q];
      L0[e] = s;
    }
    __syncthreads();
    float* wendf = (float*)(ws + WENDF_OFF);
    for (int e = tid; e < 4096; e += 256) {  // Wend[k'][n] = proj_w^T @ T3
      const int kp = e >> 6, n = e & 63;
      float s = 0.f;
      for (int m2 = 0; m2 < 64; ++m2) s += proj_w[m2 * 64 + kp] * L0[m2 * 64 + n];
      wendf[e] = s;
    }
    if (tid < 64) {
      float s = out_b[tid];
      for (int m2 = 0; m2 < 64; ++m2) s += proj_b[m2] * L0[m2 * 64 + tid];
      ((float*)(ws + BEND_OFF))[tid] = s;
    }

  } else {
    // ---- Wu = U1@o_w, Wc = S1@o_w, metric = Mm@Mm^T, bu, bc, cosd ----
    unsigned short* wu = (unsigned short*)(ws + WU_OFF);
    unsigned short* wc = (unsigned short*)(ws + WC_OFF);
    unsigned short* met = (unsigned short*)(ws + MET_OFF);
    for (int e = tid; e < 4096; e += 256) {
      const int n = e >> 6, k2 = e & 63;
      float su = 0.f, sc = 0.f, sm = 0.f;
      for (int m2 = 0; m2 < 64; ++m2) {
        const float ow = o_w[m2 * 64 + k2];
        su += update_w[n * 128 + m2] * ow;
        sc += state_w[n * 128 + m2] * ow;
        sm += metric_m[n * 64 + m2] * metric_m[k2 * 64 + m2];
      }
      wu[e] = f2bf(su); wc[e] = f2bf(sc); met[e] = f2bf(sm);
    }
    if (tid < 64) {
      float s1 = update_b[tid], s2 = state_b[tid];
      for (int m2 = 0; m2 < 64; ++m2) {
        const float ob = o_b[m2];
        s1 += update_w[tid * 128 + m2] * ob;
        s2 += state_w[tid * 128 + m2] * ob;
      }
      ((float*)(ws + BU_OFF))[tid] = s1;
      ((float*)(ws + BC_OFF))[tid] = s2;
    } else if (tid < 128) {
      const int e = tid - 64;
      ((float*)(ws + COSD_OFF))[e] =
          cosf(phase[e >> 3] - phase[e & 7]) * 0.35355339059327376f;
    }
  }
}

// =======================================================================
// Launch 2: CendT[n][i*64+j] = sum_k' connection[i][j][k'] * Wend[k'][n]
//           + tail rows CendT[n][4096+i] = Wend[i][n]
// =======================================================================
__global__ __launch_bounds__(256) void k_cend(const float* __restrict__ conn,
                                              char* __restrict__ ws)
{
  __shared__ float wl[4096];
  const int bid = blockIdx.x, tid = threadIdx.x;
  unsigned short* cendt = (unsigned short*)(ws + CENDT_OFF);
  const float* wendf = (const float*)(ws + WENDF_OFF);
  if (bid < 64) {
    for (int e = tid; e < 4096; e += 256) wl[e] = wendf[e];
    __syncthreads();
    const int i = bid;
    const int j = tid >> 2, nb = tid & 3;
    float cr[64];
    const float* cp = conn + ((size_t)i * 64 + j) * 64;
#pragma unroll
    for (int kp = 0; kp < 64; ++kp) cr[kp] = cp[kp];
    for (int n = nb * 16; n < nb * 16 + 16; ++n) {
      float s = 0.f;
#pragma unroll
      for (int kp = 0; kp < 64; ++kp) s += cr[kp] * wl[kp * 64 + n];
      cendt[(size_t)n * 4160 + i * 64 + j] = f2bf(s);
    }
  } else {
    for (int e = tid; e < 4096; e += 256) {
      const int i2 = e >> 6, n = e & 63;
      cendt[(size_t)n * 4160 + 4096 + i2] = f2bf(wendf[i2 * 64 + n]);
    }
  }
}

// =======================================================================
// Launch 3: main fused chain, 128 batch rows / block, 4 waves.
// LDS slots (bf16 [128][72], 18432 B each): S0 S1 S2 S3; then
// XM f32 [128][68] over S0+S1; Cend double-buffer 2x16KB over S2+S3.
// =======================================================================
__global__ __launch_bounds__(256, 2) void k_main(
    const float* __restrict__ q_w, const float* __restrict__ q_b,
    const float* __restrict__ k_w, const float* __restrict__ k_b,
    const float* __restrict__ v_w, const float* __restrict__ v_b,
    const char* __restrict__ ws, float* __restrict__ out)
{
  __shared__ char smem[73728];
  unsigned short* S0 = (unsigned short*)smem;
  unsigned short* S1 = (unsigned short*)(smem + 18432);
  unsigned short* S2 = (unsigned short*)(smem + 36864);
  unsigned short* S3 = (unsigned short*)(smem + 55296);
  const int tid = threadIdx.x;
  const int w = tid >> 6, lane = tid & 63;
  const int m = lane & 15, quad = lane >> 4;
  const size_t r0 = (size_t)blockIdx.x * 128;
  const unsigned short* topo_bf = (const unsigned short*)(ws + TOPO_OFF);
  const unsigned short* CENDT = (const unsigned short*)(ws + CENDT_OFF);
  const unsigned short* FINV = (const unsigned short*)(ws + FINV_OFF);
  const unsigned short* MET = (const unsigned short*)(ws + MET_OFF);
  const unsigned short* WU = (const unsigned short*)(ws + WU_OFF);
  const unsigned short* WC = (const unsigned short*)(ws + WC_OFF);
  const float* BU = (const float*)(ws + BU_OFF);
  const float* BC = (const float*)(ws + BC_OFF);
  const float* BEND = (const float*)(ws + BEND_OFF);
  const float* COSD = (const float*)(ws + COSD_OFF);

  // ---------- Phase A: q,k,v = topo @ W^T + b  ->  S0,S1,S2 (bf16) ----------
  {
    const float* Wp[3] = {q_w, k_w, v_w};
    const float* Bp[3] = {q_b, k_b, v_b};
    unsigned short* Dp[3] = {S0, S1, S2};
#pragma unroll
    for (int g3 = 0; g3 < 3; ++g3) {
      bf16x8 bfr[2][4];
#pragma unroll
      for (int ks = 0; ks < 2; ++ks)
#pragma unroll
        for (int nt = 0; nt < 4; ++nt)
          bfr[ks][nt] = ld8f32(Wp[g3] + (nt * 16 + m) * 64 + ks * 32 + quad * 8);
      float bias[4];
#pragma unroll
      for (int nt = 0; nt < 4; ++nt) bias[nt] = Bp[g3][nt * 16 + m];
#pragma unroll
      for (int mi = 0; mi < 2; ++mi) {
        const int mt = w * 2 + mi;
        f32x4 acc[4] = {};
#pragma unroll
        for (int ks = 0; ks < 2; ++ks) {
          bf16x8 a = ld8bf(topo_bf + (r0 + mt * 16 + m) * 64 + ks * 32 + quad * 8);
#pragma unroll
          for (int nt = 0; nt < 4; ++nt) acc[nt] = mfma16(a, bfr[ks][nt], acc[nt]);
        }
#pragma unroll
        for (int nt = 0; nt < 4; ++nt)
#pragma unroll
          for (int r = 0; r < 4; ++r)
            Dp[g3][(mt * 16 + quad * 4 + r) * 72 + nt * 16 + m] =
                f2bf(acc[nt][r] + bias[nt]);
      }
    }
  }
  __syncthreads();

  // ---------- Phase B: phase-rotated attention (real part) -> av in S3 ----------
  {
    const int bl = tid >> 1, hh = (tid & 1) * 4;
    float kvv[64];
    const uint4* krow = (const uint4*)(S1 + bl * 72);
#pragma unroll
    for (int x = 0; x < 8; ++x) {
      uint4 u = krow[x];
      unpk(u.x, kvv[x * 8 + 0], kvv[x * 8 + 1]);
      unpk(u.y, kvv[x * 8 + 2], kvv[x * 8 + 3]);
      unpk(u.z, kvv[x * 8 + 4], kvv[x * 8 + 5]);
      unpk(u.w, kvv[x * 8 + 6], kvv[x * 8 + 7]);
    }
    const uint4* qrow = (const uint4*)(S0 + bl * 72);
    const uint4* vrow = (const uint4*)(S2 + bl * 72);
#pragma unroll
    for (int hi = 0; hi < 4; ++hi) {
      const int h = hh + hi;
      float qv[8];
      {
        uint4 u = qrow[h];
        unpk(u.x, qv[0], qv[1]); unpk(u.y, qv[2], qv[3]);
        unpk(u.z, qv[4], qv[5]); unpk(u.w, qv[6], qv[7]);
      }
      float s[8];
#pragma unroll
      for (int g = 0; g < 8; ++g) {
        float a = 0.f;
#pragma unroll
        for (int d = 0; d < 8; ++d) a += qv[d] * kvv[g * 8 + d];
        s[g] = a * COSD[h * 8 + g];
      }
      float mx = s[0];
#pragma unroll
      for (int g = 1; g < 8; ++g) mx = fmaxf(mx, s[g]);
      float se = 0.f;
#pragma unroll
      for (int g = 0; g < 8; ++g) { s[g] = expf(s[g] - mx); se += s[g]; }
      const float inv = 1.f / se;
      float av[8] = {};
#pragma unroll
      for (int g = 0; g < 8; ++g) {
        const float ag = s[g] * inv;
        float vg[8];
        uint4 u = vrow[g];
        unpk(u.x, vg[0], vg[1]); unpk(u.y, vg[2], vg[3]);
        unpk(u.z, vg[4], vg[5]); unpk(u.w, vg[6], vg[7]);
#pragma unroll
        for (int d = 0; d < 8; ++d) av[d] += ag * vg[d];
      }
      unsigned int* dstp = (unsigned int*)(S3 + bl * 72 + h * 8);
#pragma unroll
      for (int d2 = 0; d2 < 4; ++d2)
        dstp[d2] = (unsigned)f2bf(av[2 * d2]) | ((unsigned)f2bf(av[2 * d2 + 1]) << 16);
    }
  }
  __syncthreads();

  // ---------- Phase C: update=sigmoid(av@Wu^T+bu)->S0 ; cand=tanh(av@Wc^T+bc)->S1 ----------
  {
#pragma unroll
    for (int g2 = 0; g2 < 2; ++g2) {
      const unsigned short* wp = g2 ? WC : WU;
      const float* bp = g2 ? BC : BU;
      unsigned short* dst = g2 ? S1 : S0;
      bf16x8 bfr[2][4];
#pragma unroll
      for (int ks = 0; ks < 2; ++ks)
#pragma unroll
        for (int nt = 0; nt < 4; ++nt)
          bfr[ks][nt] = ld8bf(wp + (nt * 16 + m) * 64 + ks * 32 + quad * 8);
      float bias[4];
#pragma unroll
      for (int nt = 0; nt < 4; ++nt) bias[nt] = bp[nt * 16 + m];
#pragma unroll
      for (int mi = 0; mi < 2; ++mi) {
        const int mt = w * 2 + mi;
        f32x4 acc[4] = {};
#pragma unroll
        for (int ks = 0; ks < 2; ++ks) {
          bf16x8 a = ld8bf(S3 + (mt * 16 + m) * 72 + ks * 32 + quad * 8);
#pragma unroll
          for (int nt = 0; nt < 4; ++nt) acc[nt] = mfma16(a, bfr[ks][nt], acc[nt]);
        }
#pragma unroll
        for (int nt = 0; nt < 4; ++nt)
#pragma unroll
          for (int r = 0; r < 4; ++r) {
            const float x = acc[nt][r] + bias[nt];
            const float y = g2 ? tanhf(x) : 1.f / (1.f + expf(-x));
            dst[(mt * 16 + quad * 4 + r) * 72 + nt * 16 + m] = f2bf(y);
          }
      }
    }
  }
  __syncthreads();

  // ---------- Phase D: new_h = update * (cand @ Finv) -> S2 ----------
  {
    bf16x8 bfr[2][4];
#pragma unroll
    for (int ks = 0; ks < 2; ++ks)
#pragma unroll
      for (int nt = 0; nt < 4; ++nt)
        bfr[ks][nt] = ld8bf(FINV + (nt * 16 + m) * 64 + ks * 32 + quad * 8);
#pragma unroll
    for (int mi = 0; mi < 2; ++mi) {
      const int mt = w * 2 + mi;
      f32x4 acc[4] = {};
#pragma unroll
      for (int ks = 0; ks < 2; ++ks) {
        bf16x8 a = ld8bf(S1 + (mt * 16 + m) * 72 + ks * 32 + quad * 8);
#pragma unroll
        for (int nt = 0; nt < 4; ++nt) acc[nt] = mfma16(a, bfr[ks][nt], acc[nt]);
      }
#pragma unroll
      for (int nt = 0; nt < 4; ++nt)
#pragma unroll
        for (int r = 0; r < 4; ++r) {
          const int row = mt * 16 + quad * 4 + r, col = nt * 16 + m;
          const float u = bf2f(S0[row * 72 + col]);
          S2[row * 72 + col] = f2bf(u * acc[nt][r]);
        }
    }
  }
  __syncthreads();

  // ---------- Phase E: xm = new_h @ metric -> XM (f32, over S0/S1) ----------
  {
    float* XM = (float*)smem;
    bf16x8 bfr[2][4];
#pragma unroll
    for (int ks = 0; ks < 2; ++ks)
#pragma unroll
      for (int nt = 0; nt < 4; ++nt)
        bfr[ks][nt] = ld8bf(MET + (nt * 16 + m) * 64 + ks * 32 + quad * 8);
#pragma unroll
    for (int mi = 0; mi < 2; ++mi) {
      const int mt = w * 2 + mi;
      f32x4 acc[4] = {};
#pragma unroll
      for (int ks = 0; ks < 2; ++ks) {
        bf16x8 a = ld8bf(S2 + (mt * 16 + m) * 72 + ks * 32 + quad * 8);
#pragma unroll
        for (int nt = 0; nt < 4; ++nt) acc[nt] = mfma16(a, bfr[ks][nt], acc[nt]);
      }
#pragma unroll
      for (int nt = 0; nt < 4; ++nt)
#pragma unroll
        for (int r = 0; r < 4; ++r)
          XM[(mt * 16 + quad * 4 + r) * 68 + nt * 16 + m] = acc[nt][r];
    }
  }
  __syncthreads();

  // ---------- Phase F: out = bend + xm@Wend + O@Cend  (O generated in regs) ----------
  {
    float* XM = (float*)smem;
    unsigned short* stg = (unsigned short*)(smem + 36864);  // 2 x 16KB
    float seg[2][2][8];
#pragma unroll
    for (int mi = 0; mi < 2; ++mi) {
      const int brow = w * 32 + mi * 16 + m;
#pragma unroll
      for (int s = 0; s < 2; ++s)
#pragma unroll
        for (int jj = 0; jj < 8; ++jj)
          seg[mi][s][jj] = XM[brow * 68 + s * 32 + quad * 8 + jj];
    }
    f32x4 acc2[2][4] = {};

    auto stage = [&](int cc, int half) {
#pragma unroll
      for (int ks = 0; ks < 4; ++ks) {
        const unsigned short* gp =
            CENDT + (size_t)(w * 16 + m) * 4160 + cc * 128 + ks * 32 + quad * 8;
        const char* lp = smem + 36864 + half * 16384 + (ks * 4 + w) * 1024;
        __builtin_amdgcn_global_load_lds(
            (const __attribute__((address_space(1))) unsigned int*)gp,
            (__attribute__((address_space(3))) unsigned int*)lp, 16, 0, 0);
      }
    };

    stage(0, 0);
    for (int cc = 0; cc < 32; ++cc) {
      __syncthreads();  // drains vmcnt: staged chunk cc is in LDS
      if (cc + 1 < 32) stage(cc + 1, (cc + 1) & 1);
      const unsigned short* buf = stg + (cc & 1) * 8192;
#pragma unroll
      for (int ks = 0; ks < 4; ++ks) {
        const int i = cc * 2 + (ks >> 1);
        const int s = ks & 1;
        bf16x8 afr[2];
#pragma unroll
        for (int mi = 0; mi < 2; ++mi) {
          const float xi = XM[(w * 32 + mi * 16 + m) * 68 + i];
          float pr[8];
#pragma unroll
          for (int jj = 0; jj < 8; ++jj) pr[jj] = xi * seg[mi][s][jj];
          afr[mi] = pack8(pr);
        }
#pragma unroll
        for (int nt = 0; nt < 4; ++nt) {
          bf16x8 bfr = ld8bf(buf + (ks * 4 + nt) * 512 + lane * 8);
          acc2[0][nt] = mfma16(afr[0], bfr, acc2[0][nt]);
          acc2[1][nt] = mfma16(afr[1], bfr, acc2[1][nt]);
        }
      }
    }
    // tail: K rows 4096..4159 -> xm @ Wend
#pragma unroll
    for (int ks = 0; ks < 2; ++ks) {
      bf16x8 afr[2];
#pragma unroll
      for (int mi = 0; mi < 2; ++mi) afr[mi] = pack8(seg[mi][ks]);
#pragma unroll
      for (int nt = 0; nt < 4; ++nt) {
        bf16x8 bfr =
            ld8bf(CENDT + (size_t)(nt * 16 + m) * 4160 + 4096 + ks * 32 + quad * 8);
        acc2[0][nt] = mfma16(afr[0], bfr, acc2[0][nt]);
        acc2[1][nt] = mfma16(afr[1], bfr, acc2[1][nt]);
      }
    }
    float bendv[4];
#pragma unroll
    for (int nt = 0; nt < 4; ++nt) bendv[nt] = BEND[nt * 16 + m];
#pragma unroll
    for (int mi = 0; mi < 2; ++mi)
#pragma unroll
      for (int nt = 0; nt < 4; ++nt)
#pragma unroll
        for (int r = 0; r < 4; ++r)
          out[(r0 + (w * 2 + mi) * 16 + quad * 4 + r) * 64 + nt * 16 + m] =
              acc2[mi][nt][r] + bendv[nt];
  }
}

// =======================================================================
extern "C" void kernel_launch(void* const* d_in, const int* in_sizes, int n_in,
                              void* d_out, int out_size, void* d_ws, size_t ws_size,
                              hipStream_t stream) {
  (void)in_sizes; (void)n_in; (void)out_size; (void)ws_size;
  const float* pers     = (const float*)d_in[1];
  const float* tk       = (const float*)d_in[2];
  const float* q_w      = (const float*)d_in[3];
  const float* q_b      = (const float*)d_in[4];
  const float* k_w      = (const float*)d_in[5];
  const float* k_b      = (const float*)d_in[6];
  const float* v_w      = (const float*)d_in[7];
  const float* v_b      = (const float*)d_in[8];
  const float* o_w      = (const float*)d_in[9];
  const float* o_b      = (const float*)d_in[10];
  const float* phase    = (const float*)d_in[11];
  const float* update_w = (const float*)d_in[12];
  const float* update_b = (const float*)d_in[13];
  const float* state_w  = (const float*)d_in[16];
  const float* state_b  = (const float*)d_in[17];
  const float* fisher_m = (const float*)d_in[18];
  const float* metric_m = (const float*)d_in[19];
  const float* conn     = (const float*)d_in[20];
  const float* proj_w   = (const float*)d_in[21];
  const float* proj_b   = (const float*)d_in[22];
  const float* obj_emb  = (const float*)d_in[23];
  const float* morph    = (const float*)d_in[24];
  const float* funct_w  = (const float*)d_in[25];
  const float* out_w    = (const float*)d_in[26];
  const float* out_b    = (const float*)d_in[27];
  char* ws = (char*)d_ws;

  hipLaunchKernelGGL(k_pretk, dim3(256), dim3(256), 0, stream, tk, ws);
  hipLaunchKernelGGL(k_setup_topo, dim3(1027), dim3(256), 0, stream,
                     pers, tk, fisher_m, morph, funct_w, obj_emb, out_w, proj_w,
                     proj_b, out_b, update_w, update_b, state_w, state_b, o_w,
                     o_b, metric_m, phase, ws);
  hipLaunchKernelGGL(k_cend, dim3(65), dim3(256), 0, stream, conn, ws);
  hipLaunchKernelGGL(k_main, dim3(512), dim3(256), 0, stream,
                     q_w, q_b, k_w, k_b, v_w, v_b, (const char*)ws,
                     (float*)d_out);
}